// Round 5
// baseline (619.661 us; speedup 1.0000x reference)
//
#include <hip/hip_runtime.h>
#include <math.h>

#define T_SEQ 2048
#define DMODEL 2048
#define DSTATE 128
#define NH 64
#define NG 8
#define HPG 8
#define HD 64
#define CH 256
#define NC 8
#define DIN 4096
#define CONVD 6144
#define DPROJ 10304
#define DPROJP 10368   // padded to 81*128 for 128-wide MFMA tiles
#define BCW 2048       // width of bf16 B|C buffer (2*NG*DSTATE)
#define DTOFF 10240    // start of dt columns in zx
#define EPS 1e-5f

typedef short v8s __attribute__((ext_vector_type(8)));
typedef float v4f __attribute__((ext_vector_type(4)));

__device__ __forceinline__ float silu_f(float x) { return x / (1.0f + __expf(-x)); }

__device__ __forceinline__ unsigned short f2b(float x) {  // fp32 -> bf16 bits, RNE
    union { float f; unsigned u; } v; v.f = x;
    unsigned r = v.u + 0x7fffu + ((v.u >> 16) & 1u);
    return (unsigned short)(r >> 16);
}
__device__ __forceinline__ float b2f(unsigned short u) {
    union { unsigned u; float f; } v; v.u = ((unsigned)u) << 16; return v.f;
}

// ---------------- fp32 -> bf16 convert (flat, with zero tail-padding), 4 elems/thread
__global__ __launch_bounds__(256) void cvt4_kernel(const float4* __restrict__ src,
                                                   ushort4* __restrict__ dst,
                                                   int n4_src, int n4_dst) {
    int i = blockIdx.x * 256 + threadIdx.x;
    if (i >= n4_dst) return;
    ushort4 o = {0, 0, 0, 0};
    if (i < n4_src) {
        float4 v = src[i];
        o.x = f2b(v.x); o.y = f2b(v.y); o.z = f2b(v.z); o.w = f2b(v.w);
    }
    dst[i] = o;
}

// ---------------- bf16 MFMA GEMM: C[M,N] = A[M,K] * B[N,K]^T
// grid(m_tiles, n_tiles): consecutive blocks share a B-tile (L2/LLC locality).
// OUTB: write bf16 output + fp32 side-store for dt columns [DTOFF, DTOFF+64).
template <int BN, bool OUTB>
__global__ __launch_bounds__(256) void gemm_bf16(const unsigned short* __restrict__ A,
                                                 const unsigned short* __restrict__ B,
                                                 float* __restrict__ Cf,
                                                 unsigned short* __restrict__ Cbo,
                                                 float* __restrict__ dtout,
                                                 int M, int N, int K) {
    constexpr int BM = 128, BK = 32;
    constexpr int NWT = BN / 32;
    constexpr int BCH = (BN * BK * 2) / 1024;
    __shared__ short sA[BM * BK];
    __shared__ short sB[BN * BK];
    const int tid = threadIdx.x;
    const int wave = tid >> 6, lane = tid & 63;
    const int m0 = blockIdx.x * BM, n0 = blockIdx.y * BN;
    const int wm = (wave >> 1) * 64;
    const int wn = (wave & 1) * (BN / 2);
    const int lr = lane & 15, kq = lane >> 4;

    v4f acc[4][NWT];
#pragma unroll
    for (int i = 0; i < 4; ++i)
#pragma unroll
        for (int j = 0; j < NWT; ++j) acc[i][j] = {0.f, 0.f, 0.f, 0.f};

    for (int k0 = 0; k0 < K; k0 += BK) {
#pragma unroll
        for (int qi = 0; qi < 2; ++qi) {
            int q = wave * 2 + qi;
            int e = q * 512 + lane * 8;
            int r = e >> 5, c = e & 31;
            __builtin_amdgcn_global_load_lds(
                (const __attribute__((address_space(1))) void*)(A + (size_t)(m0 + r) * K + k0 + c),
                (__attribute__((address_space(3))) void*)(sA + q * 512), 16, 0, 0);
        }
        for (int q = wave; q < BCH; q += 4) {
            int e = q * 512 + lane * 8;
            int r = e >> 5, c = e & 31;
            __builtin_amdgcn_global_load_lds(
                (const __attribute__((address_space(1))) void*)(B + (size_t)(n0 + r) * K + k0 + c),
                (__attribute__((address_space(3))) void*)(sB + q * 512), 16, 0, 0);
        }
        __syncthreads();
        v8s af[4], bf[NWT];
#pragma unroll
        for (int i = 0; i < 4; ++i)
            af[i] = *(const v8s*)(sA + (wm + i * 16 + lr) * BK + kq * 8);
#pragma unroll
        for (int j = 0; j < NWT; ++j)
            bf[j] = *(const v8s*)(sB + (wn + j * 16 + lr) * BK + kq * 8);
#pragma unroll
        for (int i = 0; i < 4; ++i)
#pragma unroll
            for (int j = 0; j < NWT; ++j)
                acc[i][j] = __builtin_amdgcn_mfma_f32_16x16x32_bf16(af[i], bf[j], acc[i][j], 0, 0, 0);
        __syncthreads();
    }
    const int crow = kq * 4, ccol = lr;
#pragma unroll
    for (int i = 0; i < 4; ++i)
#pragma unroll
        for (int j = 0; j < NWT; ++j) {
            const int col = n0 + wn + j * 16 + ccol;
            const int row0 = m0 + wm + i * 16 + crow;
#pragma unroll
            for (int r = 0; r < 4; ++r) {
                float v = acc[i][j][r];
                if (OUTB) {
                    Cbo[(size_t)(row0 + r) * N + col] = f2b(v);
                    if ((unsigned)(col - DTOFF) < 64u)
                        dtout[(size_t)(row0 + r) * 64 + (col - DTOFF)] = v;
                } else {
                    Cf[(size_t)(row0 + r) * N + col] = v;
                }
            }
        }
}

// ---------------- causal conv1d (width 4) + SiLU, bf16 in/out. 2 channels/thread.
// Emits Xb[t, DIN] (x slice), BCb[t, BCW] (B|C slice), Btr[c,g,n,t_local] (B transposed)
__global__ __launch_bounds__(256) void conv_kernel(const unsigned short* __restrict__ zxb,
                                                   const float* __restrict__ cw,
                                                   const float* __restrict__ cb,
                                                   unsigned short* __restrict__ Xb,
                                                   unsigned short* __restrict__ BCb,
                                                   unsigned short* __restrict__ Btr) {
    int idx2 = blockIdx.x * 256 + threadIdx.x;  // over T_SEQ*CONVD/2
    int c0 = (idx2 % (CONVD / 2)) * 2, t = idx2 / (CONVD / 2);
    float acc0 = cb[c0], acc1 = cb[c0 + 1];
#pragma unroll
    for (int k = 0; k < 4; ++k) {
        int tt = t + k - 3;
        if (tt >= 0) {
            ushort2 v = *(const ushort2*)&zxb[(size_t)tt * DPROJP + DIN + c0];
            acc0 = fmaf(b2f(v.x), cw[c0 * 4 + k], acc0);
            acc1 = fmaf(b2f(v.y), cw[(c0 + 1) * 4 + k], acc1);
        }
    }
    ushort2 o = {f2b(silu_f(acc0)), f2b(silu_f(acc1))};
    if (c0 < DIN) {
        *(ushort2*)&Xb[(size_t)t * DIN + c0] = o;
    } else {
        int bc = c0 - DIN;
        *(ushort2*)&BCb[(size_t)t * BCW + bc] = o;
        if (bc < NG * DSTATE) {  // B slice: scatter transposed
            int cc = t >> 8, tl = t & 255;
            Btr[((size_t)cc * (NG * DSTATE) + bc) * CH + tl] = o.x;
            Btr[((size_t)cc * (NG * DSTATE) + bc + 1) * CH + tl] = o.y;
        }
    }
}

// ---------------- dt = softplus(dt_raw + bias); dA_cs = cumsum(dt*A) within chunk
__global__ __launch_bounds__(256) void dt_kernel(const float* __restrict__ dt_raw,
                                                 const float* __restrict__ A,
                                                 const float* __restrict__ dt_bias,
                                                 float* __restrict__ dt_s,
                                                 float* __restrict__ dAcs) {
    __shared__ float s[CH];
    int h = blockIdx.x % NH, c = blockIdx.x / NH;
    int t = threadIdx.x;
    int tg = c * CH + t;
    float raw = dt_raw[(size_t)tg * 64 + h] + dt_bias[h];
    float dtv = (raw > 20.0f) ? raw : log1pf(__expf(raw));
    s[t] = dtv * A[h];
    __syncthreads();
    for (int off = 1; off < CH; off <<= 1) {
        float add = (t >= off) ? s[t - off] : 0.0f;
        __syncthreads();
        s[t] += add;
        __syncthreads();
    }
    dt_s[h * T_SEQ + tg] = dtv;
    dAcs[h * T_SEQ + tg] = s[t];
}

// ---------------- transpose Xb -> Xt[(c,h,p)][t] bf16 (chunk-local t)
__global__ __launch_bounds__(256) void xt_kernel(const unsigned short* __restrict__ Xb,
                                                 unsigned short* __restrict__ Xt) {
    __shared__ unsigned short sh[CH][72];
    const int h = blockIdx.x % NH, c = blockIdx.x / NH;
    const int tid = threadIdx.x;
    const int p = tid & 63, t4 = tid >> 6;
    for (int i = 0; i < 64; ++i) {
        int t = i * 4 + t4;
        sh[t][p] = Xb[(size_t)(c * CH + t) * DIN + h * HD + p];
    }
    __syncthreads();
    const int p2 = tid >> 2, tq = tid & 3;
    ushort4* dst = (ushort4*)(Xt + ((size_t)(c * NH + h) * HD + p2) * CH + tq * 64);
    for (int jb = 0; jb < 16; ++jb) {
        int t = tq * 64 + jb * 4;
        ushort4 v = {sh[t][p2], sh[t + 1][p2], sh[t + 2][p2], sh[t + 3][p2]};
        dst[jb] = v;
    }
}

// ---------------- fused intra-chunk: S = C·B^T (MFMA), decay/dt/causal mask, P·X (MFMA) + D·x
__global__ __launch_bounds__(256) void y1_mfma(const unsigned short* __restrict__ BCb,
                                               const unsigned short* __restrict__ Xt,
                                               const unsigned short* __restrict__ Xb,
                                               const float* __restrict__ dt_s,
                                               const float* __restrict__ dAcs,
                                               const float* __restrict__ Dp,
                                               float* __restrict__ yacc) {
    __shared__ float s_da[CH], s_dt[CH];
    __shared__ unsigned short pw[4][4][16][40];
    const int h = blockIdx.x % NH, c = blockIdx.x / NH, g = h >> 3;
    const int tid = threadIdx.x, wave = tid >> 6, lane = tid & 63;
    const int lr = lane & 15, quad = lane >> 4;
    s_da[tid] = dAcs[h * T_SEQ + c * CH + tid];
    s_dt[tid] = dt_s[h * T_SEQ + c * CH + tid];
    __syncthreads();

    const unsigned short* Cb = BCb + (size_t)c * CH * BCW + NG * DSTATE + g * DSTATE;
    const unsigned short* Bb = BCb + (size_t)c * CH * BCW + g * DSTATE;
    const unsigned short* Xr = Xt + (size_t)(c * NH + h) * HD * CH;

    v4f Y[4][4];
#pragma unroll
    for (int i = 0; i < 4; ++i)
#pragma unroll
        for (int j = 0; j < 4; ++j) Y[i][j] = {0.f, 0.f, 0.f, 0.f};

    for (int tb = 0; tb < 8; ++tb) {
        if (12 + wave < 2 * tb) continue;
        v8s bfr[2][4];
#pragma unroll
        for (int j = 0; j < 2; ++j)
#pragma unroll
            for (int ks = 0; ks < 4; ++ks)
                bfr[j][ks] = *(const v8s*)(Bb + (size_t)(tb * 32 + j * 16 + lr) * BCW + ks * 32 + quad * 8);
#pragma unroll
        for (int i = 0; i < 4; ++i) {
            int st = i * 4 + wave;
            if (st < 2 * tb) continue;
            v4f S0 = {0.f, 0.f, 0.f, 0.f}, S1 = {0.f, 0.f, 0.f, 0.f};
#pragma unroll
            for (int ks = 0; ks < 4; ++ks) {
                v8s af = *(const v8s*)(Cb + (size_t)(st * 16 + lr) * BCW + ks * 32 + quad * 8);
                S0 = __builtin_amdgcn_mfma_f32_16x16x32_bf16(af, bfr[0][ks], S0, 0, 0, 0);
                S1 = __builtin_amdgcn_mfma_f32_16x16x32_bf16(af, bfr[1][ks], S1, 0, 0, 0);
            }
            int t0 = tb * 32 + lr;
            float da0 = s_da[t0], dt0 = s_dt[t0];
            float da1 = s_da[t0 + 16], dt1 = s_dt[t0 + 16];
#pragma unroll
            for (int r = 0; r < 4; ++r) {
                int s = st * 16 + quad * 4 + r;
                float das = s_da[s];
                float w0 = (t0 <= s) ? S0[r] * __expf(das - da0) * dt0 : 0.f;
                float w1 = (t0 + 16 <= s) ? S1[r] * __expf(das - da1) * dt1 : 0.f;
                pw[wave][i][quad * 4 + r][lr] = f2b(w0);
                pw[wave][i][quad * 4 + r][16 + lr] = f2b(w1);
            }
        }
        v8s xf[4];
#pragma unroll
        for (int pj = 0; pj < 4; ++pj)
            xf[pj] = *(const v8s*)(Xr + (size_t)(pj * 16 + lr) * CH + tb * 32 + quad * 8);
#pragma unroll
        for (int i = 0; i < 4; ++i) {
            int st = i * 4 + wave;
            if (st < 2 * tb) continue;
            v8s pf = *(const v8s*)(&pw[wave][i][lr][quad * 8]);
#pragma unroll
            for (int pj = 0; pj < 4; ++pj)
                Y[i][pj] = __builtin_amdgcn_mfma_f32_16x16x32_bf16(pf, xf[pj], Y[i][pj], 0, 0, 0);
        }
    }
    const float Dh = Dp[h];
#pragma unroll
    for (int i = 0; i < 4; ++i) {
        int st = i * 4 + wave;
#pragma unroll
        for (int pj = 0; pj < 4; ++pj) {
            int p = pj * 16 + lr;
#pragma unroll
            for (int r = 0; r < 4; ++r) {
                int s = st * 16 + quad * 4 + r;
                float xv = b2f(Xb[(size_t)(c * CH + s) * DIN + h * HD + p]);
                yacc[(size_t)(c * CH + s) * DIN + h * HD + p] = Y[i][pj][r] + Dh * xv;
            }
        }
    }
}

// ---------------- MFMA states: states[c,h,p,n] = sum_t Xt[p,t] * (w2[t]*Btr[n,t])
__global__ __launch_bounds__(256) void states_mfma(const unsigned short* __restrict__ Xt,
                                                   const unsigned short* __restrict__ Btr,
                                                   const float* __restrict__ dt_s,
                                                   const float* __restrict__ dAcs,
                                                   float* __restrict__ states) {
    __shared__ float w2sh[CH];
    const int h = blockIdx.x % NH, c = blockIdx.x / NH, g = h >> 3;
    const int tid = threadIdx.x, wave = tid >> 6, lane = tid & 63;
    const int lr = lane & 15, quad = lane >> 4;
    float da_last = dAcs[h * T_SEQ + c * CH + CH - 1];
    w2sh[tid] = __expf(da_last - dAcs[h * T_SEQ + c * CH + tid]) * dt_s[h * T_SEQ + c * CH + tid];
    __syncthreads();
    const unsigned short* Xr = Xt + (size_t)(c * NH + h) * HD * CH;
    const unsigned short* Br = Btr + (size_t)(c * NG + g) * DSTATE * CH;

    v4f acc[4][2];
#pragma unroll
    for (int i = 0; i < 4; ++i)
#pragma unroll
        for (int j = 0; j < 2; ++j) acc[i][j] = {0.f, 0.f, 0.f, 0.f};

    for (int kb = 0; kb < 8; ++kb) {
        const int t0 = kb * 32 + quad * 8;
        float w[8];
        {
            float4 wa = *(const float4*)&w2sh[t0];
            float4 wb = *(const float4*)&w2sh[t0 + 4];
            w[0] = wa.x; w[1] = wa.y; w[2] = wa.z; w[3] = wa.w;
            w[4] = wb.x; w[5] = wb.y; w[6] = wb.z; w[7] = wb.w;
        }
        v8s bf[2];
#pragma unroll
        for (int j = 0; j < 2; ++j) {
            v8s raw = *(const v8s*)(Br + (size_t)(wave * 32 + j * 16 + lr) * CH + t0);
            v8s o;
#pragma unroll
            for (int e = 0; e < 8; ++e) o[e] = (short)f2b(b2f((unsigned short)raw[e]) * w[e]);
            bf[j] = o;
        }
        v8s af[4];
#pragma unroll
        for (int i = 0; i < 4; ++i)
            af[i] = *(const v8s*)(Xr + (size_t)(i * 16 + lr) * CH + t0);
#pragma unroll
        for (int i = 0; i < 4; ++i)
#pragma unroll
            for (int j = 0; j < 2; ++j)
                acc[i][j] = __builtin_amdgcn_mfma_f32_16x16x32_bf16(af[i], bf[j], acc[i][j], 0, 0, 0);
    }
#pragma unroll
    for (int i = 0; i < 4; ++i)
#pragma unroll
        for (int j = 0; j < 2; ++j)
#pragma unroll
            for (int r = 0; r < 4; ++r)
                states[((size_t)(c * NH + h) * HD + i * 16 + quad * 4 + r) * DSTATE +
                       wave * 32 + j * 16 + lr] = acc[i][j][r];
}

// ---------------- sequential chunk scan: prev_b[c] (bf16) = carry before chunk c
__global__ __launch_bounds__(256) void scan_kernel(const float* __restrict__ states,
                                                   const float* __restrict__ dAcs,
                                                   unsigned short* __restrict__ prev_b) {
    int h = blockIdx.x;
    int base = threadIdx.x * 32;
    float carry[32] = {};
    for (int c = 0; c < NC; ++c) {
        size_t off = (size_t)(c * NH + h) * (HD * DSTATE) + base;
#pragma unroll
        for (int j = 0; j < 32; ++j) prev_b[off + j] = f2b(carry[j]);
        float cd = __expf(dAcs[h * T_SEQ + c * CH + CH - 1]);
#pragma unroll
        for (int j = 0; j < 32; ++j) carry[j] = fmaf(carry[j], cd, states[off + j]);
    }
}

// ---------------- MFMA Y2: yacc[s,p] += exp(dAcs[s]) * sum_n Cb[s,n]*prev_b[p,n]
__global__ __launch_bounds__(256) void y2_mfma(const unsigned short* __restrict__ BCb,
                                               const unsigned short* __restrict__ prev_b,
                                               const float* __restrict__ dAcs,
                                               float* __restrict__ yacc) {
    __shared__ float s_da[CH];
    const int h = blockIdx.x % NH, c = blockIdx.x / NH, g = h >> 3;
    const int tid = threadIdx.x, wave = tid >> 6, lane = tid & 63;
    const int lr = lane & 15, quad = lane >> 4;
    s_da[tid] = dAcs[h * T_SEQ + c * CH + tid];
    __syncthreads();
    const unsigned short* Cb = BCb + (size_t)c * CH * BCW + NG * DSTATE + g * DSTATE;
    const unsigned short* Pr = prev_b + (size_t)(c * NH + h) * HD * DSTATE;

    v4f acc[4][4];
#pragma unroll
    for (int i = 0; i < 4; ++i)
#pragma unroll
        for (int j = 0; j < 4; ++j) acc[i][j] = {0.f, 0.f, 0.f, 0.f};

#pragma unroll
    for (int kb = 0; kb < 4; ++kb) {
        const int n0 = kb * 32 + quad * 8;
        v8s bfp[4];
#pragma unroll
        for (int pj = 0; pj < 4; ++pj)
            bfp[pj] = *(const v8s*)(Pr + (size_t)(pj * 16 + lr) * DSTATE + n0);
#pragma unroll
        for (int i = 0; i < 4; ++i) {
            v8s af = *(const v8s*)(Cb + (size_t)((wave * 4 + i) * 16 + lr) * BCW + n0);
#pragma unroll
            for (int pj = 0; pj < 4; ++pj)
                acc[i][pj] = __builtin_amdgcn_mfma_f32_16x16x32_bf16(af, bfp[pj], acc[i][pj], 0, 0, 0);
        }
    }
#pragma unroll
    for (int i = 0; i < 4; ++i) {
#pragma unroll
        for (int r = 0; r < 4; ++r) {
            int s = (wave * 4 + i) * 16 + quad * 4 + r;
            float e = __expf(s_da[s]);
            size_t base = (size_t)(c * CH + s) * DIN + h * HD;
#pragma unroll
            for (int pj = 0; pj < 4; ++pj) {
                int p = pj * 16 + lr;
                yacc[base + p] += e * acc[i][pj][r];
            }
        }
    }
}

// ---------------- gate with silu(z) (bf16 z), grouped RMSNorm; emits bf16
__global__ __launch_bounds__(256) void norm_kernel(const unsigned short* __restrict__ zxb,
                                                   const float* __restrict__ yacc,
                                                   const float* __restrict__ norm_w,
                                                   unsigned short* __restrict__ ynorm) {
    __shared__ float red[4];
    int t = blockIdx.x / NG, g = blockIdx.x % NG;
    int tid = threadIdx.x;
    int j1 = g * 512 + tid, j2 = j1 + 256;
    float v1 = yacc[(size_t)t * DIN + j1] * silu_f(b2f(zxb[(size_t)t * DPROJP + j1]));
    float v2 = yacc[(size_t)t * DIN + j2] * silu_f(b2f(zxb[(size_t)t * DPROJP + j2]));
    float ss = v1 * v1 + v2 * v2;
#pragma unroll
    for (int off = 32; off > 0; off >>= 1) ss += __shfl_down(ss, off, 64);
    if ((tid & 63) == 0) red[tid >> 6] = ss;
    __syncthreads();
    float var = (red[0] + red[1] + red[2] + red[3]) * (1.0f / 512.0f);
    float scale = rsqrtf(var + EPS);
    ynorm[(size_t)t * DIN + j1] = f2b(v1 * scale * norm_w[j1]);
    ynorm[(size_t)t * DIN + j2] = f2b(v2 * scale * norm_w[j2]);
}

extern "C" void kernel_launch(void* const* d_in, const int* in_sizes, int n_in,
                              void* d_out, int out_size, void* d_ws, size_t ws_size,
                              hipStream_t stream) {
    const float* hidden     = (const float*)d_in[0];
    const float* in_proj_w  = (const float*)d_in[1];
    const float* conv_w     = (const float*)d_in[2];
    const float* conv_b     = (const float*)d_in[3];
    const float* A          = (const float*)d_in[4];
    const float* Dp         = (const float*)d_in[5];
    const float* dt_bias    = (const float*)d_in[6];
    const float* norm_w     = (const float*)d_in[7];
    const float* out_proj_w = (const float*)d_in[8];
    float* out = (float*)d_out;

    // workspace layout (fp32 words) — total 34,209,792 words = 136.8 MB
    float* ws     = (float*)d_ws;
    unsigned short* zxb = (unsigned short*)ws;          // bf16 [T, DPROJP]: 10,616,832 w
    float* dt_raw = ws + 10616832;                      // fp32 [T, 64]:       131,072 w
    float* dt_s   = dt_raw + 131072;                    //                     131,072 w
    float* dAcs   = dt_s + 131072;                      //                     131,072 w
    float* yacc   = dAcs + 131072;                      // fp32 [T, DIN]:    8,388,608 w
    float* regE   = yacc + 8388608;                     //                  10,616,832 w
    float* regF   = regE + 10616832;                    //                   4,194,304 w

    // regE phases: inw_b (gemm1) -> Xb [0,4.2M) + Xt [4.2M,8.4M) -> states over Xb
    //              -> outw_b over Xt -> ynorm_b over states
    unsigned short* inw_b    = (unsigned short*)regE;
    unsigned short* Xb       = (unsigned short*)regE;               // conv -> y1
    unsigned short* Xt_b     = (unsigned short*)(regE + 4194304);   // xt -> states
    float*          states   = regE;                                // states_mfma -> scan
    unsigned short* outw_b   = (unsigned short*)(regE + 4194304);   // cvt -> out-proj
    unsigned short* ynorm_b  = (unsigned short*)regE;               // norm -> out-proj
    // regF phases: hidden_b (gemm1) -> BCb [0,2.1M) + Btr [2.1M,3.15M) -> prev_b over [2.1M,4.2M)
    unsigned short* hidden_b = (unsigned short*)regF;
    unsigned short* BCb      = (unsigned short*)regF;               // conv -> y2
    unsigned short* Btr      = (unsigned short*)(regF + 2097152);   // conv -> states
    unsigned short* prev_b   = (unsigned short*)(regF + 2097152);   // scan -> y2

    // --- convert inputs to bf16
    {
        int n4s = DPROJ * DMODEL / 4, n4d = DPROJP * DMODEL / 4;
        cvt4_kernel<<<(n4d + 255) / 256, 256, 0, stream>>>((const float4*)in_proj_w, (ushort4*)inw_b, n4s, n4d);
        int h4 = T_SEQ * DMODEL / 4;
        cvt4_kernel<<<(h4 + 255) / 256, 256, 0, stream>>>((const float4*)hidden, (ushort4*)hidden_b, h4, h4);
    }
    // --- in-proj GEMM: bf16 out + fp32 dt side-channel. grid(m,n) for L2 locality.
    gemm_bf16<128, true><<<dim3(T_SEQ / 128, DPROJP / 128), 256, 0, stream>>>(
        hidden_b, inw_b, nullptr, zxb, dt_raw, T_SEQ, DPROJP, DMODEL);

    conv_kernel<<<(T_SEQ * CONVD / 2) / 256, 256, 0, stream>>>(zxb, conv_w, conv_b, Xb, BCb, Btr);
    dt_kernel<<<NC * NH, CH, 0, stream>>>(dt_raw, A, dt_bias, dt_s, dAcs);
    xt_kernel<<<NC * NH, 256, 0, stream>>>(Xb, Xt_b);
    y1_mfma<<<NC * NH, 256, 0, stream>>>(BCb, Xt_b, Xb, dt_s, dAcs, Dp, yacc);
    states_mfma<<<NC * NH, 256, 0, stream>>>(Xt_b, Btr, dt_s, dAcs, states);
    scan_kernel<<<NH, 256, 0, stream>>>(states, dAcs, prev_b);
    y2_mfma<<<NC * NH, 256, 0, stream>>>(BCb, prev_b, dAcs, yacc);

    // --- convert out-proj weights (Xt dead now)
    {
        int w4 = DMODEL * DIN / 4;
        cvt4_kernel<<<(w4 + 255) / 256, 256, 0, stream>>>((const float4*)out_proj_w, (ushort4*)outw_b, w4, w4);
    }
    norm_kernel<<<T_SEQ * NG, 256, 0, stream>>>(zxb, yacc, norm_w, ynorm_b);
    // --- out-proj GEMM (fp32 out)
    gemm_bf16<64, false><<<dim3(T_SEQ / 128, DMODEL / 64), 256, 0, stream>>>(
        ynorm_b, outw_b, out, nullptr, nullptr, T_SEQ, DMODEL, DIN);
}

// Round 6
// 571.497 us; speedup vs baseline: 1.0843x; 1.0843x over previous
//
#include <hip/hip_runtime.h>
#include <math.h>

#define T_SEQ 2048
#define DMODEL 2048
#define DSTATE 128
#define NH 64
#define NG 8
#define HPG 8
#define HD 64
#define CH 256
#define NC 8
#define DIN 4096
#define CONVD 6144
#define DPROJ 10304
#define DPROJP 10368   // padded to 81*128 for 128-wide MFMA tiles
#define BCW 2048       // width of bf16 B|C buffer (2*NG*DSTATE)
#define DTOFF 10240    // start of dt columns in zx
#define EPS 1e-5f

typedef short v8s __attribute__((ext_vector_type(8)));
typedef float v4f __attribute__((ext_vector_type(4)));

__device__ __forceinline__ float silu_f(float x) { return x / (1.0f + __expf(-x)); }

__device__ __forceinline__ unsigned short f2b(float x) {  // fp32 -> bf16 bits, RNE
    union { float f; unsigned u; } v; v.f = x;
    unsigned r = v.u + 0x7fffu + ((v.u >> 16) & 1u);
    return (unsigned short)(r >> 16);
}
__device__ __forceinline__ float b2f(unsigned short u) {
    union { unsigned u; float f; } v; v.u = ((unsigned)u) << 16; return v.f;
}

// ---------------- fp32 -> bf16 convert (flat, with zero tail-padding), 4 elems/thread
__global__ __launch_bounds__(256) void cvt4_kernel(const float4* __restrict__ src,
                                                   ushort4* __restrict__ dst,
                                                   int n4_src, int n4_dst) {
    int i = blockIdx.x * 256 + threadIdx.x;
    if (i >= n4_dst) return;
    ushort4 o = {0, 0, 0, 0};
    if (i < n4_src) {
        float4 v = src[i];
        o.x = f2b(v.x); o.y = f2b(v.y); o.z = f2b(v.z); o.w = f2b(v.w);
    }
    dst[i] = o;
}

// ---------------- bf16 MFMA GEMM: C[M,N] = A[M,K] * B[N,K]^T
// grid(m_tiles, n_tiles): consecutive blocks share a B-tile (L2/LLC locality).
// OUTB: write bf16 output + fp32 side-store for dt columns [DTOFF, DTOFF+64).
template <int BN, bool OUTB>
__global__ __launch_bounds__(256) void gemm_bf16(const unsigned short* __restrict__ A,
                                                 const unsigned short* __restrict__ B,
                                                 float* __restrict__ Cf,
                                                 unsigned short* __restrict__ Cbo,
                                                 float* __restrict__ dtout,
                                                 int M, int N, int K) {
    constexpr int BM = 128, BK = 32;
    constexpr int NWT = BN / 32;
    constexpr int BCH = (BN * BK * 2) / 1024;
    __shared__ short sA[BM * BK];
    __shared__ short sB[BN * BK];
    const int tid = threadIdx.x;
    const int wave = tid >> 6, lane = tid & 63;
    const int m0 = blockIdx.x * BM, n0 = blockIdx.y * BN;
    const int wm = (wave >> 1) * 64;
    const int wn = (wave & 1) * (BN / 2);
    const int lr = lane & 15, kq = lane >> 4;

    v4f acc[4][NWT];
#pragma unroll
    for (int i = 0; i < 4; ++i)
#pragma unroll
        for (int j = 0; j < NWT; ++j) acc[i][j] = {0.f, 0.f, 0.f, 0.f};

    for (int k0 = 0; k0 < K; k0 += BK) {
#pragma unroll
        for (int qi = 0; qi < 2; ++qi) {
            int q = wave * 2 + qi;
            int e = q * 512 + lane * 8;
            int r = e >> 5, c = e & 31;
            __builtin_amdgcn_global_load_lds(
                (const __attribute__((address_space(1))) void*)(A + (size_t)(m0 + r) * K + k0 + c),
                (__attribute__((address_space(3))) void*)(sA + q * 512), 16, 0, 0);
        }
        for (int q = wave; q < BCH; q += 4) {
            int e = q * 512 + lane * 8;
            int r = e >> 5, c = e & 31;
            __builtin_amdgcn_global_load_lds(
                (const __attribute__((address_space(1))) void*)(B + (size_t)(n0 + r) * K + k0 + c),
                (__attribute__((address_space(3))) void*)(sB + q * 512), 16, 0, 0);
        }
        __syncthreads();
        v8s af[4], bf[NWT];
#pragma unroll
        for (int i = 0; i < 4; ++i)
            af[i] = *(const v8s*)(sA + (wm + i * 16 + lr) * BK + kq * 8);
#pragma unroll
        for (int j = 0; j < NWT; ++j)
            bf[j] = *(const v8s*)(sB + (wn + j * 16 + lr) * BK + kq * 8);
#pragma unroll
        for (int i = 0; i < 4; ++i)
#pragma unroll
            for (int j = 0; j < NWT; ++j)
                acc[i][j] = __builtin_amdgcn_mfma_f32_16x16x32_bf16(af[i], bf[j], acc[i][j], 0, 0, 0);
        __syncthreads();
    }
    const int crow = kq * 4, ccol = lr;
#pragma unroll
    for (int i = 0; i < 4; ++i)
#pragma unroll
        for (int j = 0; j < NWT; ++j) {
            const int col = n0 + wn + j * 16 + ccol;
            const int row0 = m0 + wm + i * 16 + crow;
#pragma unroll
            for (int r = 0; r < 4; ++r) {
                float v = acc[i][j][r];
                if (OUTB) {
                    Cbo[(size_t)(row0 + r) * N + col] = f2b(v);
                    if ((unsigned)(col - DTOFF) < 64u)
                        dtout[(size_t)(row0 + r) * 64 + (col - DTOFF)] = v;
                } else {
                    Cf[(size_t)(row0 + r) * N + col] = v;
                }
            }
        }
}

// ---------------- causal conv1d (width 4) + SiLU, bf16 in/out, 4 channels/thread.
// x slice -> Xt[(c,h,p)][t_local] (transposed scatter); B|C -> BCb row-major;
// B slice additionally -> Btr[c,g,n,t_local] (transposed scatter).
// Consecutive blocks = consecutive t so the stride-512B scatters write-combine in L2.
__global__ __launch_bounds__(256) void conv_kernel(const unsigned short* __restrict__ zxb,
                                                   const float* __restrict__ cw,
                                                   const float* __restrict__ cb,
                                                   unsigned short* __restrict__ Xt,
                                                   unsigned short* __restrict__ BCb,
                                                   unsigned short* __restrict__ Btr) {
    const int bid = blockIdx.x;             // T_SEQ * 6 blocks
    const int t = bid & (T_SEQ - 1);
    const int cg = bid >> 11;
    const int c0 = cg * 1024 + threadIdx.x * 4;
    const float4 w0 = ((const float4*)cw)[c0];
    const float4 w1 = ((const float4*)cw)[c0 + 1];
    const float4 w2 = ((const float4*)cw)[c0 + 2];
    const float4 w3 = ((const float4*)cw)[c0 + 3];
    float a0 = cb[c0], a1 = cb[c0 + 1], a2 = cb[c0 + 2], a3 = cb[c0 + 3];
#pragma unroll
    for (int k = 0; k < 4; ++k) {
        int tt = t + k - 3;
        if (tt >= 0) {
            ushort4 v = *(const ushort4*)&zxb[(size_t)tt * DPROJP + DIN + c0];
            float wk0 = (k == 0) ? w0.x : (k == 1) ? w0.y : (k == 2) ? w0.z : w0.w;
            float wk1 = (k == 0) ? w1.x : (k == 1) ? w1.y : (k == 2) ? w1.z : w1.w;
            float wk2 = (k == 0) ? w2.x : (k == 1) ? w2.y : (k == 2) ? w2.z : w2.w;
            float wk3 = (k == 0) ? w3.x : (k == 1) ? w3.y : (k == 2) ? w3.z : w3.w;
            a0 = fmaf(b2f(v.x), wk0, a0);
            a1 = fmaf(b2f(v.y), wk1, a1);
            a2 = fmaf(b2f(v.z), wk2, a2);
            a3 = fmaf(b2f(v.w), wk3, a3);
        }
    }
    unsigned short o0 = f2b(silu_f(a0)), o1 = f2b(silu_f(a1));
    unsigned short o2 = f2b(silu_f(a2)), o3 = f2b(silu_f(a3));
    const int cc = t >> 8, tl = t & 255;
    if (cg < 4) {  // x slice: scatter transposed; h = ch>>6, p = ch&63
        const int h = c0 >> 6, p = c0 & 63;
        unsigned short* dst = Xt + ((size_t)(cc * NH + h) * HD + p) * CH + tl;
        dst[0] = o0; dst[CH] = o1; dst[2 * CH] = o2; dst[3 * CH] = o3;
    } else {
        const int bc = c0 - DIN;
        ushort4 o = {o0, o1, o2, o3};
        *(ushort4*)&BCb[(size_t)t * BCW + bc] = o;
        if (bc < NG * DSTATE) {
            unsigned short* dst = Btr + ((size_t)cc * (NG * DSTATE) + bc) * CH + tl;
            dst[0] = o0; dst[CH] = o1; dst[2 * CH] = o2; dst[3 * CH] = o3;
        }
    }
}

// ---------------- dt = softplus(dt_raw + bias); dA_cs = cumsum(dt*A) within chunk
__global__ __launch_bounds__(256) void dt_kernel(const float* __restrict__ dt_raw,
                                                 const float* __restrict__ A,
                                                 const float* __restrict__ dt_bias,
                                                 float* __restrict__ dt_s,
                                                 float* __restrict__ dAcs) {
    __shared__ float s[CH];
    int h = blockIdx.x % NH, c = blockIdx.x / NH;
    int t = threadIdx.x;
    int tg = c * CH + t;
    float raw = dt_raw[(size_t)tg * 64 + h] + dt_bias[h];
    float dtv = (raw > 20.0f) ? raw : log1pf(__expf(raw));
    s[t] = dtv * A[h];
    __syncthreads();
    for (int off = 1; off < CH; off <<= 1) {
        float add = (t >= off) ? s[t - off] : 0.0f;
        __syncthreads();
        s[t] += add;
        __syncthreads();
    }
    dt_s[h * T_SEQ + tg] = dtv;
    dAcs[h * T_SEQ + tg] = s[t];
}

// ---------------- fused intra-chunk + chunk-state kernel, one block per (c,h):
//  S = C·B^T (MFMA) -> decay/dt/causal mask, D folded into diagonal -> P·X (MFMA)
//  states[p,n] = sum_t Xt[p,t]*(w2[t]*Btr[n,t])  (MFMA, reuses xf frags)
__global__ __launch_bounds__(256) void y1_mfma(const unsigned short* __restrict__ BCb,
                                               const unsigned short* __restrict__ Xt,
                                               const unsigned short* __restrict__ Btr,
                                               const float* __restrict__ dt_s,
                                               const float* __restrict__ dAcs,
                                               const float* __restrict__ Dp,
                                               float* __restrict__ yacc,
                                               float* __restrict__ states) {
    __shared__ float s_da[CH], s_dt[CH], w2sh[CH];
    __shared__ unsigned short pw[4][16][40];  // [wave][s16][t32 pad->40], one s-tile at a time
    const int h = blockIdx.x % NH, c = blockIdx.x / NH, g = h >> 3;
    const int tid = threadIdx.x, wave = tid >> 6, lane = tid & 63;
    const int lr = lane & 15, quad = lane >> 4;
    s_da[tid] = dAcs[h * T_SEQ + c * CH + tid];
    s_dt[tid] = dt_s[h * T_SEQ + c * CH + tid];
    __syncthreads();
    w2sh[tid] = __expf(s_da[CH - 1] - s_da[tid]) * s_dt[tid];
    __syncthreads();

    const unsigned short* Cb = BCb + (size_t)c * CH * BCW + NG * DSTATE + g * DSTATE;
    const unsigned short* Bb = BCb + (size_t)c * CH * BCW + g * DSTATE;
    const unsigned short* Xr = Xt + (size_t)(c * NH + h) * HD * CH;
    const unsigned short* Br = Btr + (size_t)(c * NG + g) * DSTATE * CH;
    const float Dh = Dp[h];

    v4f Y[4][4];    // [st_local][pj]
    v4f accS[4][2]; // [pj][n-half] — this wave covers n = wave*32 .. wave*32+31
#pragma unroll
    for (int i = 0; i < 4; ++i)
#pragma unroll
        for (int j = 0; j < 4; ++j) Y[i][j] = {0.f, 0.f, 0.f, 0.f};
#pragma unroll
    for (int i = 0; i < 4; ++i)
#pragma unroll
        for (int j = 0; j < 2; ++j) accS[i][j] = {0.f, 0.f, 0.f, 0.f};

    for (int tb = 0; tb < 8; ++tb) {
        const int t0q = tb * 32 + quad * 8;
        // x fragments: B-operand for P·X and A-operand for states (same layout)
        v8s xf[4];
#pragma unroll
        for (int pj = 0; pj < 4; ++pj)
            xf[pj] = *(const v8s*)(Xr + (size_t)(pj * 16 + lr) * CH + t0q);

        // ---- states: B-frag = w2-scaled Btr rows
        {
            float w[8];
            float4 wa = *(const float4*)&w2sh[t0q];
            float4 wb = *(const float4*)&w2sh[t0q + 4];
            w[0] = wa.x; w[1] = wa.y; w[2] = wa.z; w[3] = wa.w;
            w[4] = wb.x; w[5] = wb.y; w[6] = wb.z; w[7] = wb.w;
            v8s bS[2];
#pragma unroll
            for (int j = 0; j < 2; ++j) {
                v8s raw = *(const v8s*)(Br + (size_t)(wave * 32 + j * 16 + lr) * CH + t0q);
                v8s o;
#pragma unroll
                for (int e = 0; e < 8; ++e) o[e] = (short)f2b(b2f((unsigned short)raw[e]) * w[e]);
                bS[j] = o;
            }
#pragma unroll
            for (int pj = 0; pj < 4; ++pj)
#pragma unroll
                for (int j = 0; j < 2; ++j)
                    accS[pj][j] = __builtin_amdgcn_mfma_f32_16x16x32_bf16(xf[pj], bS[j], accS[pj][j], 0, 0, 0);
        }

        // ---- intra-chunk score/apply (causal tiles only)
        if (12 + wave >= 2 * tb) {
            v8s bfr[2][4];
#pragma unroll
            for (int j = 0; j < 2; ++j)
#pragma unroll
                for (int ks = 0; ks < 4; ++ks)
                    bfr[j][ks] = *(const v8s*)(Bb + (size_t)(tb * 32 + j * 16 + lr) * BCW + ks * 32 + quad * 8);
#pragma unroll
            for (int i = 0; i < 4; ++i) {
                int st = i * 4 + wave;
                if (st < 2 * tb) continue;
                v4f S0 = {0.f, 0.f, 0.f, 0.f}, S1 = {0.f, 0.f, 0.f, 0.f};
#pragma unroll
                for (int ks = 0; ks < 4; ++ks) {
                    v8s af = *(const v8s*)(Cb + (size_t)(st * 16 + lr) * BCW + ks * 32 + quad * 8);
                    S0 = __builtin_amdgcn_mfma_f32_16x16x32_bf16(af, bfr[0][ks], S0, 0, 0, 0);
                    S1 = __builtin_amdgcn_mfma_f32_16x16x32_bf16(af, bfr[1][ks], S1, 0, 0, 0);
                }
                int t0 = tb * 32 + lr;
                float da0 = s_da[t0], dt0 = s_dt[t0];
                float da1 = s_da[t0 + 16], dt1 = s_dt[t0 + 16];
#pragma unroll
                for (int r = 0; r < 4; ++r) {
                    int s = st * 16 + quad * 4 + r;
                    float das = s_da[s];
                    float w0 = (t0 <= s) ? S0[r] * __expf(das - da0) * dt0 : 0.f;
                    float w1 = (t0 + 16 <= s) ? S1[r] * __expf(das - da1) * dt1 : 0.f;
                    if (t0 == s) w0 += Dh;            // D folded into diagonal
                    if (t0 + 16 == s) w1 += Dh;
                    pw[wave][quad * 4 + r][lr] = f2b(w0);
                    pw[wave][quad * 4 + r][16 + lr] = f2b(w1);
                }
                // same-wave LDS round-trip (no barrier): P tile -> A-frag
                v8s pf = *(const v8s*)(&pw[wave][lr][quad * 8]);
#pragma unroll
                for (int pj = 0; pj < 4; ++pj)
                    Y[i][pj] = __builtin_amdgcn_mfma_f32_16x16x32_bf16(pf, xf[pj], Y[i][pj], 0, 0, 0);
            }
        }
    }
    // epilogue: Y -> yacc
#pragma unroll
    for (int i = 0; i < 4; ++i) {
        int st = i * 4 + wave;
#pragma unroll
        for (int pj = 0; pj < 4; ++pj) {
            int p = pj * 16 + lr;
#pragma unroll
            for (int r = 0; r < 4; ++r) {
                int s = st * 16 + quad * 4 + r;
                yacc[(size_t)(c * CH + s) * DIN + h * HD + p] = Y[i][pj][r];
            }
        }
    }
    // epilogue: accS -> states[(c,h,p),n]
#pragma unroll
    for (int pj = 0; pj < 4; ++pj)
#pragma unroll
        for (int j = 0; j < 2; ++j)
#pragma unroll
            for (int r = 0; r < 4; ++r)
                states[((size_t)(c * NH + h) * HD + pj * 16 + quad * 4 + r) * DSTATE +
                       wave * 32 + j * 16 + lr] = accS[pj][j][r];
}

// ---------------- sequential chunk scan: prev_b[c] (bf16) = carry before chunk c
__global__ __launch_bounds__(256) void scan_kernel(const float* __restrict__ states,
                                                   const float* __restrict__ dAcs,
                                                   unsigned short* __restrict__ prev_b) {
    int h = blockIdx.x;
    int base = threadIdx.x * 32;
    float carry[32] = {};
    for (int c = 0; c < NC; ++c) {
        size_t off = (size_t)(c * NH + h) * (HD * DSTATE) + base;
#pragma unroll
        for (int j = 0; j < 32; ++j) prev_b[off + j] = f2b(carry[j]);
        float cd = __expf(dAcs[h * T_SEQ + c * CH + CH - 1]);
#pragma unroll
        for (int j = 0; j < 32; ++j) carry[j] = fmaf(carry[j], cd, states[off + j]);
    }
}

// ---------------- MFMA Y2: yacc[s,p] += exp(dAcs[s]) * sum_n Cb[s,n]*prev_b[p,n]
__global__ __launch_bounds__(256) void y2_mfma(const unsigned short* __restrict__ BCb,
                                               const unsigned short* __restrict__ prev_b,
                                               const float* __restrict__ dAcs,
                                               float* __restrict__ yacc) {
    __shared__ float s_da[CH];
    const int h = blockIdx.x % NH, c = blockIdx.x / NH, g = h >> 3;
    const int tid = threadIdx.x, wave = tid >> 6, lane = tid & 63;
    const int lr = lane & 15, quad = lane >> 4;
    s_da[tid] = dAcs[h * T_SEQ + c * CH + tid];
    __syncthreads();
    const unsigned short* Cb = BCb + (size_t)c * CH * BCW + NG * DSTATE + g * DSTATE;
    const unsigned short* Pr = prev_b + (size_t)(c * NH + h) * HD * DSTATE;

    v4f acc[4][4];
#pragma unroll
    for (int i = 0; i < 4; ++i)
#pragma unroll
        for (int j = 0; j < 4; ++j) acc[i][j] = {0.f, 0.f, 0.f, 0.f};

#pragma unroll
    for (int kb = 0; kb < 4; ++kb) {
        const int n0 = kb * 32 + quad * 8;
        v8s bfp[4];
#pragma unroll
        for (int pj = 0; pj < 4; ++pj)
            bfp[pj] = *(const v8s*)(Pr + (size_t)(pj * 16 + lr) * DSTATE + n0);
#pragma unroll
        for (int i = 0; i < 4; ++i) {
            v8s af = *(const v8s*)(Cb + (size_t)((wave * 4 + i) * 16 + lr) * BCW + n0);
#pragma unroll
            for (int pj = 0; pj < 4; ++pj)
                acc[i][pj] = __builtin_amdgcn_mfma_f32_16x16x32_bf16(af, bfp[pj], acc[i][pj], 0, 0, 0);
        }
    }
#pragma unroll
    for (int i = 0; i < 4; ++i) {
#pragma unroll
        for (int r = 0; r < 4; ++r) {
            int s = (wave * 4 + i) * 16 + quad * 4 + r;
            float e = __expf(s_da[s]);
            size_t base = (size_t)(c * CH + s) * DIN + h * HD;
#pragma unroll
            for (int pj = 0; pj < 4; ++pj) {
                int p = pj * 16 + lr;
                yacc[base + p] += e * acc[i][pj][r];
            }
        }
    }
}

// ---------------- gate with silu(z) (bf16 z), grouped RMSNorm; vectorized 4/thread
__global__ __launch_bounds__(128) void norm_kernel(const unsigned short* __restrict__ zxb,
                                                   const float* __restrict__ yacc,
                                                   const float* __restrict__ norm_w,
                                                   unsigned short* __restrict__ ynorm) {
    __shared__ float red[2];
    int t = blockIdx.x / NG, g = blockIdx.x % NG;
    int tid = threadIdx.x;
    int j = g * 512 + tid * 4;
    float4 y4 = *(const float4*)&yacc[(size_t)t * DIN + j];
    ushort4 z4 = *(const ushort4*)&zxb[(size_t)t * DPROJP + j];
    float v0 = y4.x * silu_f(b2f(z4.x));
    float v1 = y4.y * silu_f(b2f(z4.y));
    float v2 = y4.z * silu_f(b2f(z4.z));
    float v3 = y4.w * silu_f(b2f(z4.w));
    float ss = v0 * v0 + v1 * v1 + v2 * v2 + v3 * v3;
#pragma unroll
    for (int off = 32; off > 0; off >>= 1) ss += __shfl_down(ss, off, 64);
    if ((tid & 63) == 0) red[tid >> 6] = ss;
    __syncthreads();
    float var = (red[0] + red[1]) * (1.0f / 512.0f);
    float scale = rsqrtf(var + EPS);
    float4 w4 = *(const float4*)&norm_w[j];
    ushort4 o = {f2b(v0 * scale * w4.x), f2b(v1 * scale * w4.y),
                 f2b(v2 * scale * w4.z), f2b(v3 * scale * w4.w)};
    *(ushort4*)&ynorm[(size_t)t * DIN + j] = o;
}

extern "C" void kernel_launch(void* const* d_in, const int* in_sizes, int n_in,
                              void* d_out, int out_size, void* d_ws, size_t ws_size,
                              hipStream_t stream) {
    const float* hidden     = (const float*)d_in[0];
    const float* in_proj_w  = (const float*)d_in[1];
    const float* conv_w     = (const float*)d_in[2];
    const float* conv_b     = (const float*)d_in[3];
    const float* A          = (const float*)d_in[4];
    const float* Dp         = (const float*)d_in[5];
    const float* dt_bias    = (const float*)d_in[6];
    const float* norm_w     = (const float*)d_in[7];
    const float* out_proj_w = (const float*)d_in[8];
    float* out = (float*)d_out;

    // workspace layout (fp32 words) — total 34,209,792 words = 136.8 MB
    float* ws     = (float*)d_ws;
    unsigned short* zxb = (unsigned short*)ws;          // bf16 [T, DPROJP]: 10,616,832 w
    float* dt_raw = ws + 10616832;                      //                     131,072 w
    float* dt_s   = dt_raw + 131072;                    //                     131,072 w
    float* dAcs   = dt_s + 131072;                      //                     131,072 w
    float* yacc   = dAcs + 131072;                      // fp32 [T, DIN]:    8,388,608 w
    float* regE   = yacc + 8388608;                     //                  10,616,832 w
    float* regF   = regE + 10616832;                    //                   4,194,304 w

    // regE phases: inw_b (gemm1, 42.5MB) -> Xt [0,4.19M) + states [4.19M,8.39M)
    //              -> outw_b [0,8.39M) after scan
    unsigned short* inw_b  = (unsigned short*)regE;
    unsigned short* Xt_b   = (unsigned short*)regE;                 // conv -> y1
    float*          states = regE + 4194304;                        // y1 -> scan
    unsigned short* outw_b = (unsigned short*)regE;                 // cvt -> out-proj
    // regF phases: hidden_b (gemm1) -> BCb [0,2.1M) + Btr [2.1M,3.15M)
    //              -> prev_b [2.1M,4.19M) over Btr after y1 -> ynorm_b [0,4.19M) after y2
    unsigned short* hidden_b = (unsigned short*)regF;
    unsigned short* BCb      = (unsigned short*)regF;
    unsigned short* Btr      = (unsigned short*)(regF + 2097152);
    unsigned short* prev_b   = (unsigned short*)(regF + 2097152);
    unsigned short* ynorm_b  = (unsigned short*)regF;

    // --- convert inputs to bf16
    {
        int n4s = DPROJ * DMODEL / 4, n4d = DPROJP * DMODEL / 4;
        cvt4_kernel<<<(n4d + 255) / 256, 256, 0, stream>>>((const float4*)in_proj_w, (ushort4*)inw_b, n4s, n4d);
        int h4 = T_SEQ * DMODEL / 4;
        cvt4_kernel<<<(h4 + 255) / 256, 256, 0, stream>>>((const float4*)hidden, (ushort4*)hidden_b, h4, h4);
    }
    // --- in-proj GEMM: bf16 out + fp32 dt side-channel
    gemm_bf16<128, true><<<dim3(T_SEQ / 128, DPROJP / 128), 256, 0, stream>>>(
        hidden_b, inw_b, nullptr, zxb, dt_raw, T_SEQ, DPROJP, DMODEL);

    conv_kernel<<<T_SEQ * 6, 256, 0, stream>>>(zxb, conv_w, conv_b, Xt_b, BCb, Btr);
    dt_kernel<<<NC * NH, CH, 0, stream>>>(dt_raw, A, dt_bias, dt_s, dAcs);
    y1_mfma<<<NC * NH, 256, 0, stream>>>(BCb, Xt_b, Btr, dt_s, dAcs, Dp, yacc, states);
    scan_kernel<<<NH, 256, 0, stream>>>(states, dAcs, prev_b);
    y2_mfma<<<NC * NH, 256, 0, stream>>>(BCb, prev_b, dAcs, yacc);

    // --- convert out-proj weights (Xt + states dead now)
    {
        int w4 = DMODEL * DIN / 4;
        cvt4_kernel<<<(w4 + 255) / 256, 256, 0, stream>>>((const float4*)out_proj_w, (ushort4*)outw_b, w4, w4);
    }
    norm_kernel<<<T_SEQ * NG, 128, 0, stream>>>(zxb, yacc, norm_w, ynorm_b);
    // --- out-proj GEMM (fp32 out, BN=128)
    gemm_bf16<128, false><<<dim3(T_SEQ / 128, DMODEL / 128), 256, 0, stream>>>(
        ynorm_b, outw_b, out, nullptr, nullptr, T_SEQ, DMODEL, DIN);
}

// Round 7
// 481.781 us; speedup vs baseline: 1.2862x; 1.1862x over previous
//
#include <hip/hip_runtime.h>
#include <math.h>

#define T_SEQ 2048
#define DMODEL 2048
#define DSTATE 128
#define NH 64
#define NG 8
#define HPG 8
#define HD 64
#define CH 256
#define NC 8
#define DIN 4096
#define CONVD 6144
#define DPROJ 10304
#define DPROJP 10368   // padded to 81*128 for 128-wide MFMA tiles
#define BCW 2048       // width of bf16 B|C buffer (2*NG*DSTATE)
#define DTOFF 10240    // start of dt columns in zx
#define EPS 1e-5f

typedef short v8s __attribute__((ext_vector_type(8)));
typedef float v4f __attribute__((ext_vector_type(4)));

__device__ __forceinline__ float silu_f(float x) { return x / (1.0f + __expf(-x)); }

__device__ __forceinline__ unsigned short f2b(float x) {  // fp32 -> bf16 bits, RNE
    union { float f; unsigned u; } v; v.f = x;
    unsigned r = v.u + 0x7fffu + ((v.u >> 16) & 1u);
    return (unsigned short)(r >> 16);
}
__device__ __forceinline__ float b2f(unsigned short u) {
    union { unsigned u; float f; } v; v.u = ((unsigned)u) << 16; return v.f;
}

// ---------------- fp32 -> bf16 convert (flat, with zero tail-padding), 4 elems/thread
__global__ __launch_bounds__(256) void cvt4_kernel(const float4* __restrict__ src,
                                                   ushort4* __restrict__ dst,
                                                   int n4_src, int n4_dst) {
    int i = blockIdx.x * 256 + threadIdx.x;
    if (i >= n4_dst) return;
    ushort4 o = {0, 0, 0, 0};
    if (i < n4_src) {
        float4 v = src[i];
        o.x = f2b(v.x); o.y = f2b(v.y); o.z = f2b(v.z); o.w = f2b(v.w);
    }
    dst[i] = o;
}

// ---------------- bf16 MFMA GEMM: C[M,N] = A[M,K] * B[N,K]^T
// grid(m_tiles, n_tiles): consecutive blocks share a B-tile (L2/LLC locality).
// OUTB: write bf16 output + fp32 side-store for dt columns [DTOFF, DTOFF+64).
template <int BN, bool OUTB>
__global__ __launch_bounds__(256) void gemm_bf16(const unsigned short* __restrict__ A,
                                                 const unsigned short* __restrict__ B,
                                                 float* __restrict__ Cf,
                                                 unsigned short* __restrict__ Cbo,
                                                 float* __restrict__ dtout,
                                                 int M, int N, int K) {
    constexpr int BM = 128, BK = 32;
    constexpr int NWT = BN / 32;
    constexpr int BCH = (BN * BK * 2) / 1024;
    __shared__ short sA[BM * BK];
    __shared__ short sB[BN * BK];
    const int tid = threadIdx.x;
    const int wave = tid >> 6, lane = tid & 63;
    const int m0 = blockIdx.x * BM, n0 = blockIdx.y * BN;
    const int wm = (wave >> 1) * 64;
    const int wn = (wave & 1) * (BN / 2);
    const int lr = lane & 15, kq = lane >> 4;

    v4f acc[4][NWT];
#pragma unroll
    for (int i = 0; i < 4; ++i)
#pragma unroll
        for (int j = 0; j < NWT; ++j) acc[i][j] = {0.f, 0.f, 0.f, 0.f};

    for (int k0 = 0; k0 < K; k0 += BK) {
#pragma unroll
        for (int qi = 0; qi < 2; ++qi) {
            int q = wave * 2 + qi;
            int e = q * 512 + lane * 8;
            int r = e >> 5, c = e & 31;
            __builtin_amdgcn_global_load_lds(
                (const __attribute__((address_space(1))) void*)(A + (size_t)(m0 + r) * K + k0 + c),
                (__attribute__((address_space(3))) void*)(sA + q * 512), 16, 0, 0);
        }
        for (int q = wave; q < BCH; q += 4) {
            int e = q * 512 + lane * 8;
            int r = e >> 5, c = e & 31;
            __builtin_amdgcn_global_load_lds(
                (const __attribute__((address_space(1))) void*)(B + (size_t)(n0 + r) * K + k0 + c),
                (__attribute__((address_space(3))) void*)(sB + q * 512), 16, 0, 0);
        }
        __syncthreads();
        v8s af[4], bf[NWT];
#pragma unroll
        for (int i = 0; i < 4; ++i)
            af[i] = *(const v8s*)(sA + (wm + i * 16 + lr) * BK + kq * 8);
#pragma unroll
        for (int j = 0; j < NWT; ++j)
            bf[j] = *(const v8s*)(sB + (wn + j * 16 + lr) * BK + kq * 8);
#pragma unroll
        for (int i = 0; i < 4; ++i)
#pragma unroll
            for (int j = 0; j < NWT; ++j)
                acc[i][j] = __builtin_amdgcn_mfma_f32_16x16x32_bf16(af[i], bf[j], acc[i][j], 0, 0, 0);
        __syncthreads();
    }
    const int crow = kq * 4, ccol = lr;
#pragma unroll
    for (int i = 0; i < 4; ++i)
#pragma unroll
        for (int j = 0; j < NWT; ++j) {
            const int col = n0 + wn + j * 16 + ccol;
            const int row0 = m0 + wm + i * 16 + crow;
#pragma unroll
            for (int r = 0; r < 4; ++r) {
                float v = acc[i][j][r];
                if (OUTB) {
                    Cbo[(size_t)(row0 + r) * N + col] = f2b(v);
                    if ((unsigned)(col - DTOFF) < 64u)
                        dtout[(size_t)(row0 + r) * 64 + (col - DTOFF)] = v;
                } else {
                    Cf[(size_t)(row0 + r) * N + col] = v;
                }
            }
        }
}

// ---------------- causal conv1d (width 4) + SiLU with LDS transpose.
// Block = (chunk cc, 64-channel group). Sliding-window registers for taps,
// coalesced row reads, padded-LDS transpose, coalesced row writes.
// Outputs: x slice -> Xt[(cc,h,p)][t]; B|C -> BCb[t][bc]; B also -> Btr[(cc,g,n)][t].
__global__ __launch_bounds__(256) void conv_kernel(const unsigned short* __restrict__ zxb,
                                                   const float* __restrict__ cw,
                                                   const float* __restrict__ cb,
                                                   unsigned short* __restrict__ Xt,
                                                   unsigned short* __restrict__ BCb,
                                                   unsigned short* __restrict__ Btr) {
    __shared__ unsigned short sh[64 * 262];    // [ch][t], stride 262 (odd dwords -> conflict-free)
    const int cc = blockIdx.x / 96, cg = blockIdx.x % 96;
    const int c0 = cg * 64;
    const int tid = threadIdx.x;
    const int cl = tid & 63, tq = tid >> 6;    // channel lane, t-quarter (= wave id)
    const int ch = c0 + cl;
    const float4 w = ((const float4*)cw)[ch];
    const float bias = cb[ch];
    const int tg0 = cc * 256 + tq * 64;
    float x0 = (tg0 >= 3) ? b2f(zxb[(size_t)(tg0 - 3) * DPROJP + DIN + ch]) : 0.f;
    float x1 = (tg0 >= 2) ? b2f(zxb[(size_t)(tg0 - 2) * DPROJP + DIN + ch]) : 0.f;
    float x2 = (tg0 >= 1) ? b2f(zxb[(size_t)(tg0 - 1) * DPROJP + DIN + ch]) : 0.f;
#pragma unroll 8
    for (int i = 0; i < 64; ++i) {
        float x3 = b2f(zxb[(size_t)(tg0 + i) * DPROJP + DIN + ch]);
        float acc = bias + x0 * w.x + x1 * w.y + x2 * w.z + x3 * w.w;
        sh[cl * 262 + tq * 64 + i] = f2b(silu_f(acc));
        x0 = x1; x1 = x2; x2 = x3;
    }
    __syncthreads();
    if (c0 < DIN) {
        // x slice: this block = one full head h = c0>>6, rows p = 0..63
        const int h = c0 >> 6;
        unsigned short* dst = Xt + (size_t)(cc * NH + h) * HD * CH;
#pragma unroll
        for (int it = 0; it < 8; ++it) {
            int flat = it * 256 + tid;
            int row = flat >> 5, col = (flat & 31) * 8;
            *(ushort4*)&dst[(size_t)row * CH + col]     = *(ushort4*)&sh[row * 262 + col];
            *(ushort4*)&dst[(size_t)row * CH + col + 4] = *(ushort4*)&sh[row * 262 + col + 4];
        }
    } else {
        const int bc0 = c0 - DIN;
        // BCb[t][bc]: wave-uniform t per instruction, lanes across channels (coalesced 128B)
        for (int it = 0; it < 64; ++it) {
            int t = it * 4 + tq;
            BCb[(size_t)(cc * 256 + t) * BCW + bc0 + cl] = sh[cl * 262 + t];
        }
        if (bc0 < NG * DSTATE) {
            unsigned short* dst = Btr + ((size_t)cc * (NG * DSTATE) + bc0) * CH;
#pragma unroll
            for (int it = 0; it < 8; ++it) {
                int flat = it * 256 + tid;
                int row = flat >> 5, col = (flat & 31) * 8;
                *(ushort4*)&dst[(size_t)row * CH + col]     = *(ushort4*)&sh[row * 262 + col];
                *(ushort4*)&dst[(size_t)row * CH + col + 4] = *(ushort4*)&sh[row * 262 + col + 4];
            }
        }
    }
}

// ---------------- dt = softplus(dt_raw + bias); dA_cs = cumsum(dt*A) within chunk
__global__ __launch_bounds__(256) void dt_kernel(const float* __restrict__ dt_raw,
                                                 const float* __restrict__ A,
                                                 const float* __restrict__ dt_bias,
                                                 float* __restrict__ dt_s,
                                                 float* __restrict__ dAcs) {
    __shared__ float s[CH];
    int h = blockIdx.x % NH, c = blockIdx.x / NH;
    int t = threadIdx.x;
    int tg = c * CH + t;
    float raw = dt_raw[(size_t)tg * 64 + h] + dt_bias[h];
    float dtv = (raw > 20.0f) ? raw : log1pf(__expf(raw));
    s[t] = dtv * A[h];
    __syncthreads();
    for (int off = 1; off < CH; off <<= 1) {
        float add = (t >= off) ? s[t - off] : 0.0f;
        __syncthreads();
        s[t] += add;
        __syncthreads();
    }
    dt_s[h * T_SEQ + tg] = dtv;
    dAcs[h * T_SEQ + tg] = s[t];
}

// ---------------- MFMA states: states[c,h,p,n] = sum_t Xt[p,t] * (w2[t]*Btr[n,t])
__global__ __launch_bounds__(256) void states_mfma(const unsigned short* __restrict__ Xt,
                                                   const unsigned short* __restrict__ Btr,
                                                   const float* __restrict__ dt_s,
                                                   const float* __restrict__ dAcs,
                                                   float* __restrict__ states) {
    __shared__ float w2sh[CH];
    const int h = blockIdx.x % NH, c = blockIdx.x / NH, g = h >> 3;
    const int tid = threadIdx.x, wave = tid >> 6, lane = tid & 63;
    const int lr = lane & 15, quad = lane >> 4;
    float da_last = dAcs[h * T_SEQ + c * CH + CH - 1];
    w2sh[tid] = __expf(da_last - dAcs[h * T_SEQ + c * CH + tid]) * dt_s[h * T_SEQ + c * CH + tid];
    __syncthreads();
    const unsigned short* Xr = Xt + (size_t)(c * NH + h) * HD * CH;
    const unsigned short* Br = Btr + (size_t)(c * NG + g) * DSTATE * CH;

    v4f acc[4][2];
#pragma unroll
    for (int i = 0; i < 4; ++i)
#pragma unroll
        for (int j = 0; j < 2; ++j) acc[i][j] = {0.f, 0.f, 0.f, 0.f};

    for (int kb = 0; kb < 8; ++kb) {
        const int t0 = kb * 32 + quad * 8;
        float w[8];
        {
            float4 wa = *(const float4*)&w2sh[t0];
            float4 wb = *(const float4*)&w2sh[t0 + 4];
            w[0] = wa.x; w[1] = wa.y; w[2] = wa.z; w[3] = wa.w;
            w[4] = wb.x; w[5] = wb.y; w[6] = wb.z; w[7] = wb.w;
        }
        v8s bf[2];
#pragma unroll
        for (int j = 0; j < 2; ++j) {
            v8s raw = *(const v8s*)(Br + (size_t)(wave * 32 + j * 16 + lr) * CH + t0);
            v8s o;
#pragma unroll
            for (int e = 0; e < 8; ++e) o[e] = (short)f2b(b2f((unsigned short)raw[e]) * w[e]);
            bf[j] = o;
        }
        v8s af[4];
#pragma unroll
        for (int i = 0; i < 4; ++i)
            af[i] = *(const v8s*)(Xr + (size_t)(i * 16 + lr) * CH + t0);
#pragma unroll
        for (int i = 0; i < 4; ++i)
#pragma unroll
            for (int j = 0; j < 2; ++j)
                acc[i][j] = __builtin_amdgcn_mfma_f32_16x16x32_bf16(af[i], bf[j], acc[i][j], 0, 0, 0);
    }
#pragma unroll
    for (int i = 0; i < 4; ++i)
#pragma unroll
        for (int j = 0; j < 2; ++j)
#pragma unroll
            for (int r = 0; r < 4; ++r)
                states[((size_t)(c * NH + h) * HD + i * 16 + quad * 4 + r) * DSTATE +
                       wave * 32 + j * 16 + lr] = acc[i][j][r];
}

// ---------------- sequential chunk scan, 512 blocks: prev_b[c] (bf16) = carry before chunk c
__global__ __launch_bounds__(256) void scan_kernel(const float* __restrict__ states,
                                                   const float* __restrict__ dAcs,
                                                   unsigned short* __restrict__ prev_b) {
    int h = blockIdx.x >> 3, seg = blockIdx.x & 7;
    int base = seg * 1024 + threadIdx.x * 4;
    float4 carry = {0.f, 0.f, 0.f, 0.f};
    for (int c = 0; c < NC; ++c) {
        size_t off = (size_t)(c * NH + h) * (HD * DSTATE) + base;
        ushort4 o = {f2b(carry.x), f2b(carry.y), f2b(carry.z), f2b(carry.w)};
        *(ushort4*)&prev_b[off] = o;
        float cd = __expf(dAcs[h * T_SEQ + c * CH + CH - 1]);
        float4 s = *(const float4*)&states[off];
        carry.x = fmaf(carry.x, cd, s.x);
        carry.y = fmaf(carry.y, cd, s.y);
        carry.z = fmaf(carry.z, cd, s.z);
        carry.w = fmaf(carry.w, cd, s.w);
    }
}

// ---------------- fused intra + inter chunk output, one block per (c,h):
//  inter: Y += (e^{dA_s}·C) · prev^T   (scale folded into A-frag rows)
//  intra: S = C·B^T -> decay/dt/causal mask (D on diagonal) -> Y += P·X
//  single yacc write (no RMW).
__global__ __launch_bounds__(256) void y12_mfma(const unsigned short* __restrict__ BCb,
                                                const unsigned short* __restrict__ Xt,
                                                const unsigned short* __restrict__ prev_b,
                                                const float* __restrict__ dt_s,
                                                const float* __restrict__ dAcs,
                                                const float* __restrict__ Dp,
                                                float* __restrict__ yacc) {
    __shared__ float s_da[CH], s_dt[CH];
    __shared__ unsigned short pw[4][16][40];
    const int h = blockIdx.x % NH, c = blockIdx.x / NH, g = h >> 3;
    const int tid = threadIdx.x, wave = tid >> 6, lane = tid & 63;
    const int lr = lane & 15, quad = lane >> 4;
    s_da[tid] = dAcs[h * T_SEQ + c * CH + tid];
    s_dt[tid] = dt_s[h * T_SEQ + c * CH + tid];
    __syncthreads();

    const unsigned short* Cb = BCb + (size_t)c * CH * BCW + NG * DSTATE + g * DSTATE;
    const unsigned short* Bb = BCb + (size_t)c * CH * BCW + g * DSTATE;
    const unsigned short* Xr = Xt + (size_t)(c * NH + h) * HD * CH;
    const unsigned short* Pr = prev_b + (size_t)(c * NH + h) * HD * DSTATE;
    const float Dh = Dp[h];

    v4f Y[4][4];  // [st_local][pj], st = i*4 + wave
#pragma unroll
    for (int i = 0; i < 4; ++i)
#pragma unroll
        for (int j = 0; j < 4; ++j) Y[i][j] = {0.f, 0.f, 0.f, 0.f};

    // ---- inter-chunk: Y += (e^{dA_s}·Cb) · prev^T
    {
        float es[4];
#pragma unroll
        for (int i = 0; i < 4; ++i) es[i] = __expf(s_da[(i * 4 + wave) * 16 + lr]);
#pragma unroll
        for (int kb = 0; kb < 4; ++kb) {
            const int n0 = kb * 32 + quad * 8;
            v8s bfp[4];
#pragma unroll
            for (int pj = 0; pj < 4; ++pj)
                bfp[pj] = *(const v8s*)(Pr + (size_t)(pj * 16 + lr) * DSTATE + n0);
#pragma unroll
            for (int i = 0; i < 4; ++i) {
                int st = i * 4 + wave;
                v8s raw = *(const v8s*)(Cb + (size_t)(st * 16 + lr) * BCW + n0);
                v8s af;
#pragma unroll
                for (int e = 0; e < 8; ++e) af[e] = (short)f2b(b2f((unsigned short)raw[e]) * es[i]);
#pragma unroll
                for (int pj = 0; pj < 4; ++pj)
                    Y[i][pj] = __builtin_amdgcn_mfma_f32_16x16x32_bf16(af, bfp[pj], Y[i][pj], 0, 0, 0);
            }
        }
    }

    // ---- intra-chunk (causal tiles only)
    for (int tb = 0; tb < 8; ++tb) {
        if (12 + wave < 2 * tb) continue;
        const int t0q = tb * 32 + quad * 8;
        v8s xf[4];
#pragma unroll
        for (int pj = 0; pj < 4; ++pj)
            xf[pj] = *(const v8s*)(Xr + (size_t)(pj * 16 + lr) * CH + t0q);
        v8s bfr[2][4];
#pragma unroll
        for (int j = 0; j < 2; ++j)
#pragma unroll
            for (int ks = 0; ks < 4; ++ks)
                bfr[j][ks] = *(const v8s*)(Bb + (size_t)(tb * 32 + j * 16 + lr) * BCW + ks * 32 + quad * 8);
#pragma unroll
        for (int i = 0; i < 4; ++i) {
            int st = i * 4 + wave;
            if (st < 2 * tb) continue;
            v4f S0 = {0.f, 0.f, 0.f, 0.f}, S1 = {0.f, 0.f, 0.f, 0.f};
#pragma unroll
            for (int ks = 0; ks < 4; ++ks) {
                v8s af = *(const v8s*)(Cb + (size_t)(st * 16 + lr) * BCW + ks * 32 + quad * 8);
                S0 = __builtin_amdgcn_mfma_f32_16x16x32_bf16(af, bfr[0][ks], S0, 0, 0, 0);
                S1 = __builtin_amdgcn_mfma_f32_16x16x32_bf16(af, bfr[1][ks], S1, 0, 0, 0);
            }
            int t0 = tb * 32 + lr;
            float da0 = s_da[t0], dt0 = s_dt[t0];
            float da1 = s_da[t0 + 16], dt1 = s_dt[t0 + 16];
#pragma unroll
            for (int r = 0; r < 4; ++r) {
                int s = st * 16 + quad * 4 + r;
                float das = s_da[s];
                float w0 = (t0 <= s) ? S0[r] * __expf(das - da0) * dt0 : 0.f;
                float w1 = (t0 + 16 <= s) ? S1[r] * __expf(das - da1) * dt1 : 0.f;
                if (t0 == s) w0 += Dh;            // D folded into diagonal
                if (t0 + 16 == s) w1 += Dh;
                pw[wave][quad * 4 + r][lr] = f2b(w0);
                pw[wave][quad * 4 + r][16 + lr] = f2b(w1);
            }
            v8s pf = *(const v8s*)(&pw[wave][lr][quad * 8]);  // same-wave LDS round-trip
#pragma unroll
            for (int pj = 0; pj < 4; ++pj)
                Y[i][pj] = __builtin_amdgcn_mfma_f32_16x16x32_bf16(pf, xf[pj], Y[i][pj], 0, 0, 0);
        }
    }
    // epilogue: single write
#pragma unroll
    for (int i = 0; i < 4; ++i) {
        int st = i * 4 + wave;
#pragma unroll
        for (int pj = 0; pj < 4; ++pj) {
            int p = pj * 16 + lr;
#pragma unroll
            for (int r = 0; r < 4; ++r) {
                int s = st * 16 + quad * 4 + r;
                yacc[(size_t)(c * CH + s) * DIN + h * HD + p] = Y[i][pj][r];
            }
        }
    }
}

// ---------------- gate with silu(z) (bf16 z), grouped RMSNorm; vectorized 4/thread
__global__ __launch_bounds__(128) void norm_kernel(const unsigned short* __restrict__ zxb,
                                                   const float* __restrict__ yacc,
                                                   const float* __restrict__ norm_w,
                                                   unsigned short* __restrict__ ynorm) {
    __shared__ float red[2];
    int t = blockIdx.x / NG, g = blockIdx.x % NG;
    int tid = threadIdx.x;
    int j = g * 512 + tid * 4;
    float4 y4 = *(const float4*)&yacc[(size_t)t * DIN + j];
    ushort4 z4 = *(const ushort4*)&zxb[(size_t)t * DPROJP + j];
    float v0 = y4.x * silu_f(b2f(z4.x));
    float v1 = y4.y * silu_f(b2f(z4.y));
    float v2 = y4.z * silu_f(b2f(z4.z));
    float v3 = y4.w * silu_f(b2f(z4.w));
    float ss = v0 * v0 + v1 * v1 + v2 * v2 + v3 * v3;
#pragma unroll
    for (int off = 32; off > 0; off >>= 1) ss += __shfl_down(ss, off, 64);
    if ((tid & 63) == 0) red[tid >> 6] = ss;
    __syncthreads();
    float var = (red[0] + red[1]) * (1.0f / 512.0f);
    float scale = rsqrtf(var + EPS);
    float4 w4 = *(const float4*)&norm_w[j];
    ushort4 o = {f2b(v0 * scale * w4.x), f2b(v1 * scale * w4.y),
                 f2b(v2 * scale * w4.z), f2b(v3 * scale * w4.w)};
    *(ushort4*)&ynorm[(size_t)t * DIN + j] = o;
}

extern "C" void kernel_launch(void* const* d_in, const int* in_sizes, int n_in,
                              void* d_out, int out_size, void* d_ws, size_t ws_size,
                              hipStream_t stream) {
    const float* hidden     = (const float*)d_in[0];
    const float* in_proj_w  = (const float*)d_in[1];
    const float* conv_w     = (const float*)d_in[2];
    const float* conv_b     = (const float*)d_in[3];
    const float* A          = (const float*)d_in[4];
    const float* Dp         = (const float*)d_in[5];
    const float* dt_bias    = (const float*)d_in[6];
    const float* norm_w     = (const float*)d_in[7];
    const float* out_proj_w = (const float*)d_in[8];
    float* out = (float*)d_out;

    // workspace layout (fp32 words) — total 34,209,792 words = 136.8 MB
    float* ws     = (float*)d_ws;
    unsigned short* zxb = (unsigned short*)ws;          // bf16 [T, DPROJP]: 10,616,832 w
    float* dt_raw = ws + 10616832;                      //                     131,072 w
    float* dt_s   = dt_raw + 131072;                    //                     131,072 w
    float* dAcs   = dt_s + 131072;                      //                     131,072 w
    float* yacc   = dAcs + 131072;                      // fp32 [T, DIN]:    8,388,608 w
    float* regE   = yacc + 8388608;                     //                  10,616,832 w
    float* regF   = regE + 10616832;                    //                   4,194,304 w

    // regE phases: inw_b (gemm1, 42.5MB) -> Xt [0,4.19M w) + states [4.19M,8.39M w)
    //              -> outw_b [0,4.19M w) after y12
    unsigned short* inw_b  = (unsigned short*)regE;
    unsigned short* Xt_b   = (unsigned short*)regE;                 // conv -> y12
    float*          states = regE + 4194304;                        // states_mfma -> scan
    unsigned short* outw_b = (unsigned short*)regE;                 // cvt -> out-proj
    // regF phases: hidden_b (gemm1) -> BCb [0,2.1M w) + Btr [2.1M,3.15M w)
    //              -> prev_b [2.1M,4.19M w) over Btr after states -> ynorm_b [0,4.19M w) after y12
    unsigned short* hidden_b = (unsigned short*)regF;
    unsigned short* BCb      = (unsigned short*)regF;
    unsigned short* Btr      = (unsigned short*)(regF + 2097152);
    unsigned short* prev_b   = (unsigned short*)(regF + 2097152);
    unsigned short* ynorm_b  = (unsigned short*)regF;

    // --- convert inputs to bf16
    {
        int n4s = DPROJ * DMODEL / 4, n4d = DPROJP * DMODEL / 4;
        cvt4_kernel<<<(n4d + 255) / 256, 256, 0, stream>>>((const float4*)in_proj_w, (ushort4*)inw_b, n4s, n4d);
        int h4 = T_SEQ * DMODEL / 4;
        cvt4_kernel<<<(h4 + 255) / 256, 256, 0, stream>>>((const float4*)hidden, (ushort4*)hidden_b, h4, h4);
    }
    // --- in-proj GEMM: bf16 out + fp32 dt side-channel
    gemm_bf16<128, true><<<dim3(T_SEQ / 128, DPROJP / 128), 256, 0, stream>>>(
        hidden_b, inw_b, nullptr, zxb, dt_raw, T_SEQ, DPROJP, DMODEL);

    conv_kernel<<<NC * 96, 256, 0, stream>>>(zxb, conv_w, conv_b, Xt_b, BCb, Btr);
    dt_kernel<<<NC * NH, CH, 0, stream>>>(dt_raw, A, dt_bias, dt_s, dAcs);
    states_mfma<<<NC * NH, 256, 0, stream>>>(Xt_b, Btr, dt_s, dAcs, states);
    scan_kernel<<<NH * 8, 256, 0, stream>>>(states, dAcs, prev_b);
    y12_mfma<<<NC * NH, 256, 0, stream>>>(BCb, Xt_b, prev_b, dt_s, dAcs, Dp, yacc);

    // --- convert out-proj weights (Xt + states dead now)
    {
        int w4 = DMODEL * DIN / 4;
        cvt4_kernel<<<(w4 + 255) / 256, 256, 0, stream>>>((const float4*)out_proj_w, (ushort4*)outw_b, w4, w4);
    }
    norm_kernel<<<T_SEQ * NG, 128, 0, stream>>>(zxb, yacc, norm_w, ynorm_b);
    // --- out-proj GEMM (fp32 out, BN=128)
    gemm_bf16<128, false><<<dim3(T_SEQ / 128, DMODEL / 128), 256, 0, stream>>>(
        ynorm_b, outw_b, out, nullptr, nullptr, T_SEQ, DMODEL, DIN);
}